// Round 9
// baseline (2436.734 us; speedup 1.0000x reference)
//
#include <hip/hip_runtime.h>

// Semi-CRF log-partition. B=4, T=512, L=96, W=63.
// v9: every pipeline stage software-pipelined to depth 4 so NO stage carries a
// serial global round trip per iteration (rate law: r = max per-stage iteration
// time; slack never divides latency for frontier-tracking stages).
//  - finalizer block: wave0 = core (d=1, dual-label -> single full-96 C, no
//    cross-wave handshake), waves1-5 = OFF d=2..6 (dual-label, LDS-only),
//    waves6-7 = REST pair (merge 5 slotC + 8 chain ends + z, depth-4 rolling
//    prefetch of chain-end loads).
//  - relays d=7..63 (pair per offset, split-label), 8 interleaved chains
//    (residue d mod 8, ends 7..14): 4-phase rolling pipeline; gate/chain/seg
//    loads issued 4 targets ahead; spins are validate-only.
// Cross-block handoffs: 8B relaxed agent atomics, self-validating (NaN sentinel
// in axp hi word; chain tag in low 8 mantissa bits of v).

#define Tn 512
#define Ln 96
#define HL 48
#define LSQ (Ln * Ln)
#define Wn 63
#define BPB 16
#define NEGINF (-1e30f)
#define SENT 0x7FC00000u

#define AGENT __HIP_MEMORY_SCOPE_AGENT
#define WG __HIP_MEMORY_SCOPE_WORKGROUP
#define RLX __ATOMIC_RELAXED
#define LDSF() asm volatile("s_waitcnt lgkmcnt(0)" ::: "memory")
#define CBAR() asm volatile("" ::: "memory")
#define SIDX(b, i, t) ((((size_t)(b) * Tn + (i)) * Tn + (t)) * Ln)

typedef unsigned long long u64;
typedef unsigned int u32;

__device__ __forceinline__ float wsumred(float v) {
#pragma unroll
  for (int m = 32; m >= 1; m >>= 1) v += __shfl_xor(v, m, 64);
  return v;
}
__device__ __forceinline__ u64 pack2(float lo, float hi) {
  return (u64)__float_as_uint(lo) | ((u64)__float_as_uint(hi) << 32);
}
// full-wave (64-lane) max: 4 DPP steps (max within 16) + 4 readlanes
__device__ __forceinline__ float wavemax48(float v) {
  int x;
  x = __builtin_amdgcn_update_dpp(__float_as_int(v), __float_as_int(v), 0xB1,
                                  0xF, 0xF, false);
  v = fmaxf(v, __int_as_float(x));
  x = __builtin_amdgcn_update_dpp(__float_as_int(v), __float_as_int(v), 0x4E,
                                  0xF, 0xF, false);
  v = fmaxf(v, __int_as_float(x));
  x = __builtin_amdgcn_update_dpp(__float_as_int(v), __float_as_int(v), 0x141,
                                  0xF, 0xF, false);
  v = fmaxf(v, __int_as_float(x));
  x = __builtin_amdgcn_update_dpp(__float_as_int(v), __float_as_int(v), 0x140,
                                  0xF, 0xF, false);
  v = fmaxf(v, __int_as_float(x));
  float r0 = __int_as_float(__builtin_amdgcn_readlane(__float_as_int(v), 0));
  float r1 = __int_as_float(__builtin_amdgcn_readlane(__float_as_int(v), 16));
  float r2 = __int_as_float(__builtin_amdgcn_readlane(__float_as_int(v), 32));
  float r3 = __int_as_float(__builtin_amdgcn_readlane(__float_as_int(v), 48));
  return fmaxf(fmaxf(r0, r1), fmaxf(r2, r3));
}

__global__ void init_ws(u64* ws) {
  const size_t n1 = (size_t)4 * Tn * Ln;
  const size_t n = n1 * 9;
  for (size_t i = (size_t)blockIdx.x * blockDim.x + threadIdx.x; i < n;
       i += (size_t)gridDim.x * blockDim.x)
    ws[i] = (i < n1) ? (((u64)SENT) << 32) : 0ull;
}

__global__ __launch_bounds__(512, 1) void semicrf(
    const float* __restrict__ seg, const float* __restrict__ tr,
    float* __restrict__ out, u64* axp, u64* acc) {
  const int b = blockIdx.x / BPB;
  const int role = blockIdx.x % BPB;
  const int tid = threadIdx.x;

  __shared__ __align__(16) float E[LSQ];  // exp(trans), 36 KB
  __shared__ __align__(16) char SH[22784];

  // finalizer overlay
  float* AlbR = (float*)SH;               // [8][96]
  float* CRng = (float*)(SH + 3072);      // [8]
  float* slotC = (float*)(SH + 3104);     // [8][5][96]
  float* RESTm = (float*)(SH + 18464);    // [4][96]
  float* RESTv = (float*)(SH + 20000);    // [4][96]
  int* seqA = (int*)(SH + 21536);         // [1]
  int* spOff = (int*)(SH + 21540);        // [5]
  int* rq = (int*)(SH + 21560);           // [2]
  // relay overlay
  float* Alb_s = (float*)SH;              // [4 pair][4 slot][96]
  int* stg = (int*)(SH + 6144);           // [4][2]

  for (int i = tid; i < LSQ; i += 512) E[i] = __expf(tr[i]);
  if (role == 0) {
    if (tid == 0) *seqA = -1;
    if (tid >= 1 && tid < 6) spOff[tid - 1] = -1;
    if (tid >= 6 && tid < 8) rq[tid - 6] = -1;
  } else {
    if (tid < 8) stg[tid] = -1;
  }
  __syncthreads();  // the only block-wide barrier

  if (role != 0) {
    // =============== relay pair, offset d = 7 + pg in [7..63] ===============
    const int pair = tid >> 7;
    const int tp = tid & 127;
    const int wv = tp >> 6;
    const int l = tp & 63;
    const bool act = l < HL;
    const int lab = wv * HL + (act ? l : HL - 1);
    const int pg = (role - 1) * 4 + pair;
    const int d = 7 + pg;
    if (d > Wn) return;
    const int jr = d & 7;
    const int send = Tn - d;
    u64* chain = acc + ((size_t)jr * 4 + b) * Tn * Ln;
    const u64* axB = axp + (size_t)b * Tn * Ln;
    float* AS = Alb_s + pair * (4 * Ln);
    int* stgp = stg + pair * 2;
    const bool isHead = (d >= 56);

    float R[Ln];
#pragma unroll
    for (int lp = 0; lp < Ln; ++lp) R[lp] = E[lp * Ln + lab];
    int wc = 1;

    u64 ga0, ga1, ga2, ga3, ha0 = 0, ha1 = 0, ha2 = 0, ha3 = 0;
    float fa0, fa1, fa2, fa3;
    ga0 = __hip_atomic_load(&axB[(size_t)0 * Ln + lab], RLX, AGENT);
    ga1 = __hip_atomic_load(&axB[(size_t)1 * Ln + lab], RLX, AGENT);
    ga2 = __hip_atomic_load(&axB[(size_t)2 * Ln + lab], RLX, AGENT);
    ga3 = __hip_atomic_load(&axB[(size_t)3 * Ln + lab], RLX, AGENT);
    fa0 = seg[SIDX(b, 1, d + 0) + lab];
    fa1 = seg[SIDX(b, 2, d + 1) + lab];
    fa2 = seg[SIDX(b, 3, d + 2) + lab];
    fa3 = seg[SIDX(b, 4, d + 3) + lab];

#define RPH(K, GA, HA, FA)                                                     \
  {                                                                            \
    const int s = sb + K;                                                      \
    if (s < send) {                                                            \
      const int t = s + d;                                                     \
      while ((u32)(GA >> 32) == SENT)                                          \
        GA = __hip_atomic_load(&axB[(size_t)s * Ln + lab], RLX, AGENT);        \
      const float Cs = __uint_as_float((u32)(GA >> 32));                       \
      if (act) AS[(K)*Ln + lab] = __uint_as_float((u32)GA);                    \
      LDSF();                                                                  \
      if (l == 0) __hip_atomic_store(&stgp[wv], s, RLX, WG);                   \
      if (s + 4 < send)                                                        \
        GA = __hip_atomic_load(&axB[(size_t)(s + 4) * Ln + lab], RLX, AGENT);  \
      const int w = (t <= Wn) ? (s + 1) : (64 - d);                            \
      if (w > wc) {                                                            \
        wc = w;                                                                \
        _Pragma("unroll") for (int lp = 0; lp < Ln; ++lp) R[lp] *=             \
            E[lp * Ln + lab];                                                  \
      }                                                                        \
      while (__hip_atomic_load(&stgp[wv ^ 1], RLX, WG) < s) {}                 \
      CBAR();                                                                  \
      float i0 = 0, i1 = 0, i2 = 0, i3 = 0;                                    \
      const float4* A4 = (const float4*)(AS + (K)*Ln);                         \
      _Pragma("unroll") for (int q = 0; q < 24; ++q) {                         \
        float4 a = A4[q];                                                      \
        i0 = fmaf(a.x, R[4 * q + 0], i0);                                      \
        i1 = fmaf(a.y, R[4 * q + 1], i1);                                      \
        i2 = fmaf(a.z, R[4 * q + 2], i2);                                      \
        i3 = fmaf(a.w, R[4 * q + 3], i3);                                      \
      }                                                                        \
      const float c = Cs + (float)w * FA + __logf((i0 + i1) + (i2 + i3));      \
      float m, v;                                                              \
      if (isHead || s < 8) {                                                   \
        m = c;                                                                 \
        v = 1.f;                                                               \
      } else {                                                                 \
        while (((HA >> 32) & 0xFFu) != (u32)(d + 8))                           \
          HA = __hip_atomic_load(&chain[(size_t)t * Ln + lab], RLX, AGENT);    \
        const float pm = __uint_as_float((u32)HA);                             \
        const float pv = __uint_as_float(((u32)(HA >> 32)) & ~0xFFu);          \
        const float nm = fmaxf(pm, c);                                         \
        v = pv * __expf(pm - nm) + __expf(c - nm);                             \
        m = nm;                                                                \
      }                                                                        \
      if (act) {                                                               \
        const u32 vb = (__float_as_uint(v) & ~0xFFu) | (u32)d;                 \
        __hip_atomic_store(&chain[(size_t)t * Ln + lab],                       \
                           (u64)__float_as_uint(m) | ((u64)vb << 32), RLX,     \
                           AGENT);                                             \
      }                                                                        \
      if (s + 4 < send) {                                                      \
        FA = seg[SIDX(b, s + 5, t + 4) + lab];                                 \
        if (!isHead && (s + 4 >= 8))                                           \
          HA = __hip_atomic_load(&chain[(size_t)(t + 4) * Ln + lab], RLX,      \
                                 AGENT);                                       \
      }                                                                        \
    }                                                                          \
  }

    for (int sb = 0; sb < send; sb += 4) {
      RPH(0, ga0, ha0, fa0)
      RPH(1, ga1, ha1, fa1)
      RPH(2, ga2, ha2, fa2)
      RPH(3, ga3, ha3, fa3)
    }
    return;
  }

  // =========================== finalizer block ==============================
  const int w6 = tid >> 6;
  const int l = tid & 63;

  if (w6 == 0) {
    // -------- core: d=1, dual-label single wave, merge + publish ----------
    const bool act = l < HL;
    const int la = act ? l : HL - 1;
    const int lb = la + HL;
    u64* axpB = axp + (size_t)b * Tn * Ln;
    const float bosa = tr[LSQ + la], bosb = tr[LSQ + lb];
    float Ra[Ln], Rb[Ln];
#pragma unroll
    for (int lp = 0; lp < Ln; ++lp) {
      Ra[lp] = E[lp * Ln + la];
      Rb[lp] = E[lp * Ln + lb];
    }
    int w1c = 1;
    float Cprev;
    {  // seed t=0: alpha0 = exp(seg[b,0,0,:]+bos) (reference stores exp'd)
      const float a0a = __expf(seg[SIDX(b, 0, 0) + la] + bosa);
      const float a0b = __expf(seg[SIDX(b, 0, 0) + lb] + bosb);
      const float C = wavemax48(act ? fmaxf(a0a, a0b) : NEGINF);
      const float axa = __expf(a0a - C), axb = __expf(a0b - C);
      if (act) {
        AlbR[la] = axa;
        AlbR[lb] = axb;
      }
      if (l == 0) CRng[0] = C;
      LDSF();
      if (l == 0) __hip_atomic_store(seqA, 0, RLX, WG);
      if (act) {
        __hip_atomic_store(&axpB[la], pack2(axa, C), RLX, AGENT);
        __hip_atomic_store(&axpB[lb], pack2(axb, C), RLX, AGENT);
      }
      Cprev = C;
    }
    float pa0 = seg[SIDX(b, 1, 1) + la], pb0 = seg[SIDX(b, 1, 1) + lb];
    float pa1 = seg[SIDX(b, 2, 2) + la], pb1 = seg[SIDX(b, 2, 2) + lb];

    for (int t = 1; t < Tn; ++t) {
      const int s = t - 1;
      const float sa = pa0, sbv = pb0;
      pa0 = pa1;
      pb0 = pb1;
      if (t + 2 < Tn) {
        pa1 = seg[SIDX(b, t + 2, t + 2) + la];
        pb1 = seg[SIDX(b, t + 2, t + 2) + lb];
      }
      const int w1 = (t <= Wn) ? t : Wn;
      if (w1 > w1c) {
        w1c = w1;
#pragma unroll
        for (int lp = 0; lp < Ln; ++lp) {
          Ra[lp] *= E[lp * Ln + la];
          Rb[lp] *= E[lp * Ln + lb];
        }
      }
      float x0 = 0, x1 = 0, x2 = 0, x3 = 0, y0 = 0, y1 = 0, y2 = 0, y3 = 0;
      const float4* A4 = (const float4*)(AlbR + (s & 7) * Ln);
#pragma unroll
      for (int q = 0; q < 24; ++q) {
        float4 a = A4[q];
        x0 = fmaf(a.x, Ra[4 * q + 0], x0);
        x1 = fmaf(a.y, Ra[4 * q + 1], x1);
        x2 = fmaf(a.z, Ra[4 * q + 2], x2);
        x3 = fmaf(a.w, Ra[4 * q + 3], x3);
        y0 = fmaf(a.x, Rb[4 * q + 0], y0);
        y1 = fmaf(a.y, Rb[4 * q + 1], y1);
        y2 = fmaf(a.z, Rb[4 * q + 2], y2);
        y3 = fmaf(a.w, Rb[4 * q + 3], y3);
      }
      const float w1f = (float)w1;
      const float c1a = Cprev + w1f * sa + __logf((x0 + x1) + (x2 + x3));
      const float c1b = Cprev + w1f * sbv + __logf((y0 + y1) + (y2 + y3));
      while (__hip_atomic_load(&rq[0], RLX, WG) < t) {}
      while (__hip_atomic_load(&rq[1], RLX, WG) < t) {}
      CBAR();
      const float mra = RESTm[(t & 3) * Ln + la];
      const float vra = RESTv[(t & 3) * Ln + la];
      const float mrb = RESTm[(t & 3) * Ln + lb];
      const float vrb = RESTv[(t & 3) * Ln + lb];
      const float na = fmaxf(c1a, mra);
      const float va = __expf(c1a - na) + vra * __expf(mra - na);
      const float aa = na + __logf(va);
      const float nb = fmaxf(c1b, mrb);
      const float vb2 = __expf(c1b - nb) + vrb * __expf(mrb - nb);
      const float ab = nb + __logf(vb2);
      const float C = wavemax48(act ? fmaxf(aa, ab) : NEGINF);
      const float axa = __expf(aa - C), axb = __expf(ab - C);
      if (act) {
        AlbR[(t & 7) * Ln + la] = axa;
        AlbR[(t & 7) * Ln + lb] = axb;
      }
      if (l == 0) CRng[t & 7] = C;
      LDSF();
      if (l == 0) __hip_atomic_store(seqA, t, RLX, WG);
      if (act) {
        __hip_atomic_store(&axpB[(size_t)t * Ln + la], pack2(axa, C), RLX,
                           AGENT);
        __hip_atomic_store(&axpB[(size_t)t * Ln + lb], pack2(axb, C), RLX,
                           AGENT);
      }
      Cprev = C;
      if (t == Tn - 1) {
        const float sm = wsumred(act ? (axa + axb) : 0.f);
        if (l == 0) out[b] = C + __logf(sm);
      }
    }
    return;
  }

  if (w6 <= 5) {
    // ------------- OFF wave: d = w6+1 in [2..6], dual-label ---------------
    const int d = w6 + 1;
    const bool act = l < HL;
    const int la = act ? l : HL - 1;
    const int lb = la + HL;
    float Ra[Ln], Rb[Ln];
#pragma unroll
    for (int lp = 0; lp < Ln; ++lp) {
      Ra[lp] = E[lp * Ln + la];
      Rb[lp] = E[lp * Ln + lb];
    }
    int wc = 1;
    float qa0 = seg[SIDX(b, 1, d) + la], qb0 = seg[SIDX(b, 1, d) + lb];
    float qa1 = seg[SIDX(b, 2, d + 1) + la], qb1 = seg[SIDX(b, 2, d + 1) + lb];

    for (int t = d; t < Tn; ++t) {
      const int s = t - d;
      const int w = (t <= Wn) ? (s + 1) : (64 - d);
      const float sa = qa0, sbv = qb0;
      qa0 = qa1;
      qb0 = qb1;
      if (t + 2 < Tn) {
        qa1 = seg[SIDX(b, s + 3, t + 2) + la];
        qb1 = seg[SIDX(b, s + 3, t + 2) + lb];
      }
      if (w > wc) {
        wc = w;
#pragma unroll
        for (int lp = 0; lp < Ln; ++lp) {
          Ra[lp] *= E[lp * Ln + la];
          Rb[lp] *= E[lp * Ln + lb];
        }
      }
      while (__hip_atomic_load(seqA, RLX, WG) < s) {}
      CBAR();
      const float Cs = CRng[s & 7];
      float x0 = 0, x1 = 0, x2 = 0, x3 = 0, y0 = 0, y1 = 0, y2 = 0, y3 = 0;
      const float4* A4 = (const float4*)(AlbR + (s & 7) * Ln);
#pragma unroll
      for (int q = 0; q < 24; ++q) {
        float4 a = A4[q];
        x0 = fmaf(a.x, Ra[4 * q + 0], x0);
        x1 = fmaf(a.y, Ra[4 * q + 1], x1);
        x2 = fmaf(a.z, Ra[4 * q + 2], x2);
        x3 = fmaf(a.w, Ra[4 * q + 3], x3);
        y0 = fmaf(a.x, Rb[4 * q + 0], y0);
        y1 = fmaf(a.y, Rb[4 * q + 1], y1);
        y2 = fmaf(a.z, Rb[4 * q + 2], y2);
        y3 = fmaf(a.w, Rb[4 * q + 3], y3);
      }
      const float wf = (float)w;
      const float ca = Cs + wf * sa + __logf((x0 + x1) + (x2 + x3));
      const float cb = Cs + wf * sbv + __logf((y0 + y1) + (y2 + y3));
      if (act) {
        slotC[((t & 7) * 5 + (d - 2)) * Ln + la] = ca;
        slotC[((t & 7) * 5 + (d - 2)) * Ln + lb] = cb;
      }
      LDSF();
      if (l == 0) __hip_atomic_store(&spOff[d - 2], t, RLX, WG);
    }
    return;
  }

  {
    // --------- REST wave (w6=6,7): slotC + 8 chain ends + z merge ---------
    const int rwv = w6 - 6;
    const bool act = l < HL;
    const int lab = rwv * HL + (act ? l : HL - 1);
    const float bos = tr[LSQ + lab];
    u64 CE[4][8];
    float CZ[4];
#pragma unroll
    for (int K = 0; K < 4; ++K) {
      const int t0 = 1 + K;
#pragma unroll
      for (int jjr = 0; jjr < 8; ++jjr) {
        const int ed = (jjr == 7) ? 7 : 8 + jjr;
        CE[K][jjr] = 0;
        if (t0 >= ed)
          CE[K][jjr] = __hip_atomic_load(
              &acc[(((size_t)jjr * 4 + b) * Tn + t0) * Ln + lab], RLX, AGENT);
      }
      CZ[K] = (t0 <= Wn) ? seg[SIDX(b, 0, t0) + lab] : 0.f;
    }

#define QPH(K)                                                                 \
  {                                                                            \
    const int t = tb + K;                                                      \
    if (t < Tn) {                                                              \
      if (t >= 2) {                                                            \
        while (__hip_atomic_load(&spOff[0], RLX, WG) < t) {}                   \
      }                                                                        \
      if (t >= 3) {                                                            \
        while (__hip_atomic_load(&spOff[1], RLX, WG) < t) {}                   \
      }                                                                        \
      if (t >= 4) {                                                            \
        while (__hip_atomic_load(&spOff[2], RLX, WG) < t) {}                   \
      }                                                                        \
      if (t >= 5) {                                                            \
        while (__hip_atomic_load(&spOff[3], RLX, WG) < t) {}                   \
      }                                                                        \
      if (t >= 6) {                                                            \
        while (__hip_atomic_load(&spOff[4], RLX, WG) < t) {}                   \
      }                                                                        \
      CBAR();                                                                  \
      float cc0 = NEGINF, cc1 = NEGINF, cc2 = NEGINF, cc3 = NEGINF,            \
            cc4 = NEGINF;                                                      \
      if (t >= 2) cc0 = slotC[((t & 7) * 5 + 0) * Ln + lab];                   \
      if (t >= 3) cc1 = slotC[((t & 7) * 5 + 1) * Ln + lab];                   \
      if (t >= 4) cc2 = slotC[((t & 7) * 5 + 2) * Ln + lab];                   \
      if (t >= 5) cc3 = slotC[((t & 7) * 5 + 3) * Ln + lab];                   \
      if (t >= 6) cc4 = slotC[((t & 7) * 5 + 4) * Ln + lab];                   \
      const float zv = (t <= Wn) ? (float)(t + 1) * (CZ[K] + bos) : NEGINF;    \
      float M = fmaxf(fmaxf(fmaxf(cc0, cc1), fmaxf(cc2, cc3)),                 \
                      fmaxf(cc4, zv));                                         \
      float em[8], ev[8];                                                      \
      _Pragma("unroll") for (int jjr = 0; jjr < 8; ++jjr) {                    \
        const int ed = (jjr == 7) ? 7 : 8 + jjr;                               \
        if (t >= ed) {                                                         \
          while (((CE[K][jjr] >> 32) & 0xFFu) != (u32)ed)                      \
            CE[K][jjr] = __hip_atomic_load(                                    \
                &acc[(((size_t)jjr * 4 + b) * Tn + t) * Ln + lab], RLX,        \
                AGENT);                                                        \
          em[jjr] = __uint_as_float((u32)CE[K][jjr]);                          \
          ev[jjr] = __uint_as_float(((u32)(CE[K][jjr] >> 32)) & ~0xFFu);       \
          M = fmaxf(M, em[jjr]);                                               \
        } else {                                                               \
          em[jjr] = NEGINF;                                                    \
          ev[jjr] = 0.f;                                                       \
        }                                                                      \
      }                                                                        \
      float vs = __expf(cc0 - M) + __expf(cc1 - M) + __expf(cc2 - M) +         \
                 __expf(cc3 - M) + __expf(cc4 - M) + __expf(zv - M);           \
      _Pragma("unroll") for (int jjr = 0; jjr < 8; ++jjr) vs +=                \
          ev[jjr] * __expf(em[jjr] - M);                                       \
      if (act) {                                                               \
        RESTm[(t & 3) * Ln + lab] = M;                                         \
        RESTv[(t & 3) * Ln + lab] = vs;                                        \
      }                                                                        \
      LDSF();                                                                  \
      if (l == 0) __hip_atomic_store(&rq[rwv], t, RLX, WG);                    \
      const int tn = t + 4;                                                    \
      if (tn < Tn) {                                                           \
        _Pragma("unroll") for (int jjr = 0; jjr < 8; ++jjr) {                  \
          const int ed = (jjr == 7) ? 7 : 8 + jjr;                             \
          if (tn >= ed)                                                        \
            CE[K][jjr] = __hip_atomic_load(                                    \
                &acc[(((size_t)jjr * 4 + b) * Tn + tn) * Ln + lab], RLX,       \
                AGENT);                                                        \
        }                                                                      \
        CZ[K] = (tn <= Wn) ? seg[SIDX(b, 0, tn) + lab] : 0.f;                  \
      }                                                                        \
    }                                                                          \
  }

    for (int tb = 1; tb < Tn; tb += 4) {
      QPH(0)
      QPH(1)
      QPH(2)
      QPH(3)
    }
    return;
  }
}

extern "C" void kernel_launch(void* const* d_in, const int* in_sizes, int n_in,
                              void* d_out, int out_size, void* d_ws,
                              size_t ws_size, hipStream_t stream) {
  const float* seg = (const float*)d_in[0];  // (4,512,512,96) f32
  const float* tr = (const float*)d_in[1];   // (97,96) f32
  float* out = (float*)d_out;                // (4,) f32

  u64* axp = (u64*)d_ws;                 // [4][512][96]
  u64* acc = axp + (size_t)4 * Tn * Ln;  // [8][4][512][96]

  hipLaunchKernelGGL(init_ws, dim3(2048), dim3(256), 0, stream, (u64*)d_ws);
  hipLaunchKernelGGL(semicrf, dim3(4 * BPB), dim3(512), 0, stream, seg, tr,
                     out, axp, acc);
}